// Round 2
// baseline (311.109 us; speedup 1.0000x reference)
//
#include <hip/hip_runtime.h>

#define N_NODES 20000
#define N_PAD   20032      // 313 * 64
#define DEG 32
#define D 128
#define EPS 1e-7f
#define MAX_TANH_ARG (1.0f - 1e-5f)
#define SCORE_SCALE 0.08838834764831845f   // 1/sqrt(128)

typedef short bf16x8 __attribute__((ext_vector_type(8)));
typedef float f32x4 __attribute__((ext_vector_type(4)));

__device__ __forceinline__ float b2f(unsigned short u) {
  union { unsigned int i; float f; } x; x.i = ((unsigned int)u) << 16; return x.f;
}
__device__ __forceinline__ unsigned short f2b(float f) {
  union { float f; unsigned int i; } x; x.f = f;
  unsigned int r = x.i + 0x7FFFu + ((x.i >> 16) & 1u);   // RNE
  return (unsigned short)(r >> 16);
}
// dtype flag: curvature[0] = -1.0. fp32 -> low u16 == 0x0000 ; bf16 -> 0xBF80
__device__ __forceinline__ bool inputs_are_bf16(const void* curv) {
  return *(const unsigned short*)curv != 0;
}
__device__ __forceinline__ float read_sqrt_c(const void* c) {
  unsigned short u = *(const unsigned short*)c;
  float cv = (u == 0) ? *(const float*)c : b2f(u);
  return sqrtf(fabsf(cv));
}

// ---- K_cvt: canonicalize external float arrays to bf16 (dual dtype) ------
__global__ __launch_bounds__(256) void convert_kernel(
    const void* __restrict__ s0, unsigned short* __restrict__ d0, int n0,
    const void* __restrict__ s1, unsigned short* __restrict__ d1, int n1,
    const void* __restrict__ s2, unsigned short* __restrict__ d2, int n2,
    const void* __restrict__ s3, unsigned short* __restrict__ d3, int n3,
    const void* __restrict__ curv) {
  bool bf = inputs_are_bf16(curv);
  int total = n0 + n1 + n2 + n3;
  for (int i = blockIdx.x * 256 + threadIdx.x; i < total; i += gridDim.x * 256) {
    int idx = i;
    const void* s; unsigned short* d;
    if (idx < n0)                { s = s0; d = d0; }
    else if ((idx -= n0) < n1)   { s = s1; d = d1; }
    else if ((idx -= n1) < n2)   { s = s2; d = d2; }
    else { idx -= n2;              s = s3; d = d3; }
    d[idx] = bf ? ((const unsigned short*)s)[idx]
                : f2b(((const float*)s)[idx]);
  }
}

// ---------------- K0: t = logmap0(x), output bf16 -------------------------
__global__ __launch_bounds__(256) void logmap_kernel(
    const void* __restrict__ xin, unsigned short* __restrict__ t_out,
    const void* __restrict__ curv, int external) {
  int gid  = blockIdx.x * 256 + threadIdx.x;
  int node = gid >> 6;
  int lane = gid & 63;
  if (node >= N_NODES) return;
  bool srcbf = external && inputs_are_bf16(curv);
  float2 xv;
  if (srcbf) {
    ushort2 u = ((const ushort2*)xin)[node * 64 + lane];
    xv.x = b2f(u.x); xv.y = b2f(u.y);
  } else {
    xv = ((const float2*)xin)[node * 64 + lane];
  }
  float ss = xv.x * xv.x + xv.y * xv.y;
#pragma unroll
  for (int m = 32; m >= 1; m >>= 1) ss += __shfl_xor(ss, m);
  float norm = fmaxf(sqrtf(ss), EPS);
  float sc   = read_sqrt_c(curv);
  float arg  = fminf(sc * norm, MAX_TANH_ARG);
  float s    = atanhf(arg) / (sc * norm);
  ushort2 o; o.x = f2b(xv.x * s); o.y = f2b(xv.y * s);
  ((ushort2*)t_out)[node * 64 + lane] = o;
}

// ---------------- K1: qkv = t @ W^T + b (bf16 MFMA) -----------------------
// grid (313, 6); block 256 = 4 waves; wave tile 16m x 64n, K=128
__global__ __launch_bounds__(256) void qkv_kernel(
    const short* __restrict__ t,             // [N_PAD][128] bf16
    const unsigned short* __restrict__ W,    // [384][128] bf16 canonical
    const unsigned short* __restrict__ bias, // [384] bf16 canonical
    float* __restrict__ qout,                // [N_PAD][128] f32
    unsigned short* __restrict__ kout,       // [N_PAD][128] bf16
    unsigned short* __restrict__ vout) {     // [N_PAD][128] bf16
  int wave = threadIdx.x >> 6;
  int lane = threadIdx.x & 63;
  int quad = lane >> 4;
  int l16  = lane & 15;
  int m0   = blockIdx.x * 64 + wave * 16;
  int n0   = blockIdx.y * 64;

  bf16x8 a[4];
  const short* arow = t + (size_t)(m0 + l16) * D + quad * 8;
#pragma unroll
  for (int kk = 0; kk < 4; kk++) a[kk] = *(const bf16x8*)(arow + kk * 32);

  f32x4 acc[4];
#pragma unroll
  for (int s = 0; s < 4; s++) acc[s] = {0.f, 0.f, 0.f, 0.f};

#pragma unroll
  for (int s = 0; s < 4; s++) {
    const short* brow = (const short*)W + (size_t)(n0 + s * 16 + l16) * D + quad * 8;
#pragma unroll
    for (int kk = 0; kk < 4; kk++) {
      bf16x8 bf = *(const bf16x8*)(brow + kk * 32);
      acc[s] = __builtin_amdgcn_mfma_f32_16x16x32_bf16(a[kk], bf, acc[s], 0, 0, 0);
    }
  }

  int region = n0 >> 7;  // 0 -> q ; 1 -> k ; 2 -> v  (uniform per block)
#pragma unroll
  for (int s = 0; s < 4; s++) {
    int n = n0 + s * 16 + l16;
    float bv = b2f(bias[n]);
#pragma unroll
    for (int r = 0; r < 4; r++) {
      int m = m0 + quad * 4 + r;
      if (m < N_NODES) {
        float val = acc[s][r] + bv;
        if (region == 0)      qout[(size_t)m * D + n] = val;
        else if (region == 1) kout[(size_t)m * D + (n - 128)] = f2b(val);
        else                  vout[(size_t)m * D + (n - 256)] = f2b(val);
      }
    }
  }
}

// ---------------- K2: attention (one wave per node) -----------------------
__global__ __launch_bounds__(256) void attn_kernel(
    const int* __restrict__ nbrs,
    const float* __restrict__ q,             // [N_PAD][128] f32
    const unsigned short* __restrict__ kb,   // [N_PAD][128] bf16
    const unsigned short* __restrict__ vb,   // [N_PAD][128] bf16
    unsigned short* __restrict__ hout) {     // [N_PAD][128] bf16
  int gid  = blockIdx.x * 256 + threadIdx.x;
  int node = gid >> 6;
  int lane = gid & 63;
  if (node >= N_NODES) return;

  float2 qv = ((const float2*)q)[(size_t)node * 64 + lane];
  int nbr = nbrs[node * DEG + (lane & 31)];

  float myscore = 0.f;
#pragma unroll 4
  for (int j = 0; j < DEG; j++) {
    int nj = __shfl(nbr, j);
    ushort2 kk = ((const ushort2*)kb)[(size_t)nj * 64 + lane];
    float p = b2f(kk.x) * qv.x + b2f(kk.y) * qv.y;
#pragma unroll
    for (int m = 32; m >= 1; m >>= 1) p += __shfl_xor(p, m);
    if ((lane & 31) == j) myscore = p * SCORE_SCALE;
  }
  // softmax over 32 scores (lanes j and j+32 both hold score j)
  float smax = myscore;
#pragma unroll
  for (int m = 16; m >= 1; m >>= 1) smax = fmaxf(smax, __shfl_xor(smax, m));
  float e = expf(myscore - smax);
  float ssum = e;
#pragma unroll
  for (int m = 16; m >= 1; m >>= 1) ssum += __shfl_xor(ssum, m);
  float attn = e / ssum;

  float2 hv = {0.f, 0.f};
#pragma unroll 4
  for (int j = 0; j < DEG; j++) {
    int nj = __shfl(nbr, j);
    float aw = __shfl(attn, j);
    ushort2 vv = ((const ushort2*)vb)[(size_t)nj * 64 + lane];
    hv.x += aw * b2f(vv.x);
    hv.y += aw * b2f(vv.y);
  }
  ushort2 o; o.x = f2b(hv.x); o.y = f2b(hv.y);
  ((ushort2*)hout)[(size_t)node * 64 + lane] = o;
}

// ---------------- K3: out_proj + bias + expmap0 ---------------------------
// grid 313; block 256 = 4 waves; wave tile 16m x 128n
// FINAL=true writes d_out with runtime dtype (bf16 iff inputs were bf16)
template <bool FINAL>
__global__ __launch_bounds__(256) void outproj_expmap_kernel(
    const short* __restrict__ h,             // [N_PAD][128] bf16
    const unsigned short* __restrict__ W,    // [128][128] bf16 canonical
    const unsigned short* __restrict__ bias, // [128] bf16 canonical
    void* __restrict__ xout,
    const void* __restrict__ curv) {
  __shared__ float smem[64 * 129];
  __shared__ float rowscale[64];
  int wave = threadIdx.x >> 6;
  int lane = threadIdx.x & 63;
  int quad = lane >> 4;
  int l16  = lane & 15;
  int m0   = blockIdx.x * 64 + wave * 16;

  bf16x8 a[4];
  const short* arow = h + (size_t)(m0 + l16) * D + quad * 8;
#pragma unroll
  for (int kk = 0; kk < 4; kk++) a[kk] = *(const bf16x8*)(arow + kk * 32);

  f32x4 acc[8];
#pragma unroll
  for (int s = 0; s < 8; s++) acc[s] = {0.f, 0.f, 0.f, 0.f};
#pragma unroll
  for (int s = 0; s < 8; s++) {
    const short* brow = (const short*)W + (size_t)(s * 16 + l16) * D + quad * 8;
#pragma unroll
    for (int kk = 0; kk < 4; kk++) {
      bf16x8 bf = *(const bf16x8*)(brow + kk * 32);
      acc[s] = __builtin_amdgcn_mfma_f32_16x16x32_bf16(a[kk], bf, acc[s], 0, 0, 0);
    }
  }
#pragma unroll
  for (int s = 0; s < 8; s++) {
    int n = s * 16 + l16;
    float bv = b2f(bias[n]);
#pragma unroll
    for (int r = 0; r < 4; r++) {
      int rloc = wave * 16 + quad * 4 + r;
      smem[rloc * 129 + n] = acc[s][r] + bv;
    }
  }
  __syncthreads();
  if (threadIdx.x < 64) {
    int r = threadIdx.x;
    float ss = 0.f;
#pragma unroll 8
    for (int kc = 0; kc < D; kc++) { float v = smem[r * 129 + kc]; ss += v * v; }
    float norm = fmaxf(sqrtf(ss), EPS);
    float sc = read_sqrt_c(curv);
    rowscale[r] = tanhf(sc * norm) / (sc * norm);
  }
  __syncthreads();
  bool outbf = FINAL && inputs_are_bf16(curv);
  int mbase = blockIdx.x * 64;
  for (int i = threadIdx.x; i < 64 * D; i += 256) {
    int rloc = i >> 7, col = i & 127;
    int m = mbase + rloc;
    if (m < N_NODES) {
      float val = smem[rloc * 129 + col] * rowscale[rloc];
      if (FINAL) {
        if (outbf) ((unsigned short*)xout)[(size_t)m * D + col] = f2b(val);
        else       ((float*)xout)[(size_t)m * D + col] = val;
      } else {
        ((float*)xout)[(size_t)m * D + col] = val;
      }
    }
  }
}

// --------------------------------------------------------------------------
extern "C" void kernel_launch(void* const* d_in, const int* in_sizes, int n_in,
                              void* d_out, int out_size, void* d_ws, size_t ws_size,
                              hipStream_t stream) {
  const int* neighbors = (const int*)d_in[0];
  const void* node_emb = d_in[1];
  const void* curv     = d_in[2];
  const void* in_w     = d_in[3];  // [L][384][128]
  const void* in_b     = d_in[4];  // [L][384]
  const void* out_w    = d_in[5];  // [L][128][128]
  const void* out_b    = d_in[6];  // [L][128]

  char* ws = (char*)d_ws;
  size_t off = 0;
  auto alloc = [&](size_t bytes) {
    char* p = ws + off; off += (bytes + 255) & ~(size_t)255; return p;
  };
  unsigned short* t_bf = (unsigned short*)alloc((size_t)N_PAD * D * 2);
  float*          q_f  = (float*)alloc((size_t)N_PAD * D * 4);
  unsigned short* k_bf = (unsigned short*)alloc((size_t)N_PAD * D * 2);
  unsigned short* v_bf = (unsigned short*)alloc((size_t)N_PAD * D * 2);
  float*          x1   = (float*)alloc((size_t)N_NODES * D * 4);
  const int n_inw = 2 * 384 * D, n_inb = 2 * 384, n_outw = 2 * D * D, n_outb = 2 * D;
  unsigned short* inw_bf  = (unsigned short*)alloc((size_t)n_inw * 2);
  unsigned short* inb_bf  = (unsigned short*)alloc((size_t)n_inb * 2);
  unsigned short* outw_bf = (unsigned short*)alloc((size_t)n_outw * 2);
  unsigned short* outb_bf = (unsigned short*)alloc((size_t)n_outb * 2);
  unsigned short* h_bf = t_bf;  // t dead after K1; reuse for h

  dim3 blk(256);
  int nodeBlocks = (N_NODES + 3) / 4;   // 5000
  int mTiles     = (N_NODES + 63) / 64; // 313

  convert_kernel<<<208, blk, 0, stream>>>(
      in_w, inw_bf, n_inw, in_b, inb_bf, n_inb,
      out_w, outw_bf, n_outw, out_b, outb_bf, n_outb, curv);

  for (int l = 0; l < 2; l++) {
    if (l == 0)
      logmap_kernel<<<nodeBlocks, blk, 0, stream>>>(node_emb, t_bf, curv, 1);
    else
      logmap_kernel<<<nodeBlocks, blk, 0, stream>>>(x1, t_bf, curv, 0);

    qkv_kernel<<<dim3(mTiles, 6), blk, 0, stream>>>(
        (const short*)t_bf, inw_bf + (size_t)l * 384 * D, inb_bf + (size_t)l * 384,
        q_f, k_bf, v_bf);

    attn_kernel<<<nodeBlocks, blk, 0, stream>>>(neighbors, q_f, k_bf, v_bf, h_bf);

    if (l == 0)
      outproj_expmap_kernel<false><<<mTiles, blk, 0, stream>>>(
          (const short*)h_bf, outw_bf + (size_t)l * D * D, outb_bf + (size_t)l * D,
          x1, curv);
    else
      outproj_expmap_kernel<true><<<mTiles, blk, 0, stream>>>(
          (const short*)h_bf, outw_bf + (size_t)l * D * D, outb_bf + (size_t)l * D,
          d_out, curv);
  }
}

// Round 3
// 235.433 us; speedup vs baseline: 1.3214x; 1.3214x over previous
//
#include <hip/hip_runtime.h>

#define N_NODES 20000
#define N_PAD   20032      // 313 * 64
#define DEG 32
#define D 128
#define EPS 1e-7f
#define MAX_TANH_ARG (1.0f - 1e-5f)
#define SCORE_SCALE 0.08838834764831845f   // 1/sqrt(128)

typedef short bf16x8 __attribute__((ext_vector_type(8)));
typedef float f32x4 __attribute__((ext_vector_type(4)));

__device__ __forceinline__ float b2f(unsigned short u) {
  union { unsigned int i; float f; } x; x.i = ((unsigned int)u) << 16; return x.f;
}
__device__ __forceinline__ unsigned short f2b(float f) {
  union { float f; unsigned int i; } x; x.f = f;
  unsigned int r = x.i + 0x7FFFu + ((x.i >> 16) & 1u);   // RNE
  return (unsigned short)(r >> 16);
}
// dtype flag: curvature[0] = -1.0. fp32 -> low u16 == 0x0000 ; bf16 -> 0xBF80
__device__ __forceinline__ bool inputs_are_bf16(const void* curv) {
  return *(const unsigned short*)curv != 0;
}
__device__ __forceinline__ float read_sqrt_c(const void* c) {
  unsigned short u = *(const unsigned short*)c;
  float cv = (u == 0) ? *(const float*)c : b2f(u);
  return sqrtf(fabsf(cv));
}

// ---- K_cvt: canonicalize external float arrays to bf16 (dual dtype) ------
__global__ __launch_bounds__(256) void convert_kernel(
    const void* __restrict__ s0, unsigned short* __restrict__ d0, int n0,
    const void* __restrict__ s1, unsigned short* __restrict__ d1, int n1,
    const void* __restrict__ s2, unsigned short* __restrict__ d2, int n2,
    const void* __restrict__ s3, unsigned short* __restrict__ d3, int n3,
    const void* __restrict__ curv) {
  bool bf = inputs_are_bf16(curv);
  int total = n0 + n1 + n2 + n3;
  for (int i = blockIdx.x * 256 + threadIdx.x; i < total; i += gridDim.x * 256) {
    int idx = i;
    const void* s; unsigned short* d;
    if (idx < n0)                { s = s0; d = d0; }
    else if ((idx -= n0) < n1)   { s = s1; d = d1; }
    else if ((idx -= n1) < n2)   { s = s2; d = d2; }
    else { idx -= n2;              s = s3; d = d3; }
    d[idx] = bf ? ((const unsigned short*)s)[idx]
                : f2b(((const float*)s)[idx]);
  }
}

// ------- K1: fused logmap0 + qkv GEMM (t staged in LDS, bf16 MFMA) --------
// grid 313; block 256 = 4 waves; block tile 64m x 384n, K=128
__global__ __launch_bounds__(256) void lqkv_kernel(
    const void* __restrict__ xin, int external,
    const unsigned short* __restrict__ W,    // [384][128] bf16 canonical
    const unsigned short* __restrict__ bias, // [384] bf16 canonical
    float* __restrict__ qout,                // [N_PAD][128] f32
    unsigned short* __restrict__ kout,       // [N_PAD][128] bf16
    unsigned short* __restrict__ vout,       // [N_PAD][128] bf16
    const void* __restrict__ curv) {
  __shared__ unsigned short t_lds[64 * 136];  // +8 shorts pad per row
  int lane = threadIdx.x & 63;
  int wave = threadIdx.x >> 6;
  int mbase = blockIdx.x * 64;
  bool srcbf = external && inputs_are_bf16(curv);
  float sqc = read_sqrt_c(curv);

  // ---- stage 1: t = logmap0(x) into LDS. 8 lanes per row, 16 cols/lane ---
  {
    int rl = threadIdx.x >> 3;   // 0..31
    int c8 = threadIdx.x & 7;    // 16-col chunk
#pragma unroll
    for (int pass = 0; pass < 2; pass++) {
      int r = pass * 32 + rl;
      int m = mbase + r;
      float xv[16];
      if (m < N_NODES) {
        if (srcbf) {
          const bf16x8* xp = (const bf16x8*)((const unsigned short*)xin + (size_t)m * D + c8 * 16);
          bf16x8 u0 = xp[0], u1 = xp[1];
#pragma unroll
          for (int i = 0; i < 8; i++) { xv[i] = b2f((unsigned short)u0[i]); xv[8 + i] = b2f((unsigned short)u1[i]); }
        } else {
          const float4* xp = (const float4*)((const float*)xin + (size_t)m * D + c8 * 16);
#pragma unroll
          for (int i = 0; i < 4; i++) {
            float4 v = xp[i];
            xv[i * 4 + 0] = v.x; xv[i * 4 + 1] = v.y; xv[i * 4 + 2] = v.z; xv[i * 4 + 3] = v.w;
          }
        }
      } else {
#pragma unroll
        for (int i = 0; i < 16; i++) xv[i] = 0.f;
      }
      float ss = 0.f;
#pragma unroll
      for (int i = 0; i < 16; i++) ss += xv[i] * xv[i];
      ss += __shfl_xor(ss, 1); ss += __shfl_xor(ss, 2); ss += __shfl_xor(ss, 4);
      float norm = fmaxf(sqrtf(ss), EPS);
      float arg  = fminf(sqc * norm, MAX_TANH_ARG);
      float sfac = atanhf(arg) / (sqc * norm);
      bf16x8 o0, o1;
#pragma unroll
      for (int i = 0; i < 8; i++) {
        o0[i] = (short)f2b(xv[i] * sfac);
        o1[i] = (short)f2b(xv[8 + i] * sfac);
      }
      *(bf16x8*)&t_lds[r * 136 + c8 * 16]     = o0;
      *(bf16x8*)&t_lds[r * 136 + c8 * 16 + 8] = o1;
    }
  }
  __syncthreads();

  // ---- stage 2: per wave 16m x 384n MFMA ---------------------------------
  int quad = lane >> 4, l16 = lane & 15;
  int m0 = mbase + wave * 16;
  bf16x8 a[4];
#pragma unroll
  for (int kk = 0; kk < 4; kk++)
    a[kk] = *(const bf16x8*)&t_lds[(wave * 16 + l16) * 136 + quad * 8 + kk * 32];

  for (int nt = 0; nt < 6; nt++) {
    int n0 = nt * 64;
    f32x4 acc[4];
#pragma unroll
    for (int s = 0; s < 4; s++) acc[s] = {0.f, 0.f, 0.f, 0.f};
#pragma unroll
    for (int s = 0; s < 4; s++) {
      const short* brow = (const short*)W + (size_t)(n0 + s * 16 + l16) * D + quad * 8;
#pragma unroll
      for (int kk = 0; kk < 4; kk++) {
        bf16x8 bfv = *(const bf16x8*)(brow + kk * 32);
        acc[s] = __builtin_amdgcn_mfma_f32_16x16x32_bf16(a[kk], bfv, acc[s], 0, 0, 0);
      }
    }
    int region = n0 >> 7;  // 0 -> q ; 1 -> k ; 2 -> v (uniform per nt)
#pragma unroll
    for (int s = 0; s < 4; s++) {
      int n = n0 + s * 16 + l16;
      float bv = b2f(bias[n]);
#pragma unroll
      for (int r = 0; r < 4; r++) {
        int m = m0 + quad * 4 + r;
        if (m < N_NODES) {
          float val = acc[s][r] + bv;
          if (region == 0)      qout[(size_t)m * D + n] = val;
          else if (region == 1) kout[(size_t)m * D + (n - 128)] = f2b(val);
          else                  vout[(size_t)m * D + (n - 256)] = f2b(val);
        }
      }
    }
  }
}

// ---------------- K2: attention (one wave per node, 4 nbrs/iter) ----------
__global__ __launch_bounds__(256) void attn_kernel(
    const int* __restrict__ nbrs,
    const float* __restrict__ q,             // [N_PAD][128] f32
    const unsigned short* __restrict__ kb,   // [N_PAD][128] bf16
    const unsigned short* __restrict__ vb,   // [N_PAD][128] bf16
    unsigned short* __restrict__ hout) {     // [N_PAD][128] bf16
  int gid  = blockIdx.x * 256 + threadIdx.x;
  int node = gid >> 6;
  int lane = gid & 63;
  if (node >= N_NODES) return;
  int g = lane >> 4;   // neighbor subgroup 0..3
  int s = lane & 15;   // dim slice: 8 dims at s*8

  float qr[8];
  {
    const float4* qp = (const float4*)(q + (size_t)node * D + s * 8);
    float4 q0 = qp[0], q1 = qp[1];
    qr[0] = q0.x; qr[1] = q0.y; qr[2] = q0.z; qr[3] = q0.w;
    qr[4] = q1.x; qr[5] = q1.y; qr[6] = q1.z; qr[7] = q1.w;
  }
  int idx[8];
#pragma unroll
  for (int jj = 0; jj < 8; jj++) idx[jj] = nbrs[node * DEG + jj * 4 + g];

  // scores: neighbor j = jj*4+g ; 16-lane dot reduce
  float sc[8];
#pragma unroll
  for (int jj = 0; jj < 8; jj++) {
    bf16x8 kv = *(const bf16x8*)(kb + (size_t)idx[jj] * D + s * 8);
    float p = 0.f;
#pragma unroll
    for (int i = 0; i < 8; i++) p += b2f((unsigned short)kv[i]) * qr[i];
    p += __shfl_xor(p, 1); p += __shfl_xor(p, 2);
    p += __shfl_xor(p, 4); p += __shfl_xor(p, 8);
    sc[jj] = p * SCORE_SCALE;
  }
  // softmax over 32 (8 local + 2 cross-group stages)
  float mx = sc[0];
#pragma unroll
  for (int jj = 1; jj < 8; jj++) mx = fmaxf(mx, sc[jj]);
  mx = fmaxf(mx, __shfl_xor(mx, 16));
  mx = fmaxf(mx, __shfl_xor(mx, 32));
  float sum = 0.f;
#pragma unroll
  for (int jj = 0; jj < 8; jj++) { sc[jj] = __expf(sc[jj] - mx); sum += sc[jj]; }
  sum += __shfl_xor(sum, 16);
  sum += __shfl_xor(sum, 32);
  float inv = 1.f / sum;

  float hv[8];
#pragma unroll
  for (int i = 0; i < 8; i++) hv[i] = 0.f;
#pragma unroll
  for (int jj = 0; jj < 8; jj++) {
    float aw = sc[jj] * inv;
    bf16x8 vv = *(const bf16x8*)(vb + (size_t)idx[jj] * D + s * 8);
#pragma unroll
    for (int i = 0; i < 8; i++) hv[i] += aw * b2f((unsigned short)vv[i]);
  }
#pragma unroll
  for (int i = 0; i < 8; i++) {
    hv[i] += __shfl_xor(hv[i], 16);
    hv[i] += __shfl_xor(hv[i], 32);
  }
  if (g == 0) {
    bf16x8 o;
#pragma unroll
    for (int i = 0; i < 8; i++) o[i] = (short)f2b(hv[i]);
    *(bf16x8*)(hout + (size_t)node * D + s * 8) = o;
  }
}

// ---------------- K3: out_proj + bias + expmap0 ---------------------------
// grid 313; block 256 = 4 waves; wave tile 16m x 128n
template <bool FINAL>
__global__ __launch_bounds__(256) void outproj_expmap_kernel(
    const short* __restrict__ h,             // [N_PAD][128] bf16
    const unsigned short* __restrict__ W,    // [128][128] bf16 canonical
    const unsigned short* __restrict__ bias, // [128] bf16 canonical
    void* __restrict__ xout,
    const void* __restrict__ curv) {
  __shared__ float smem[64 * 129];
  __shared__ float rowscale[64];
  int wave = threadIdx.x >> 6;
  int lane = threadIdx.x & 63;
  int quad = lane >> 4;
  int l16  = lane & 15;
  int m0   = blockIdx.x * 64 + wave * 16;

  bf16x8 a[4];
  const short* arow = h + (size_t)(m0 + l16) * D + quad * 8;
#pragma unroll
  for (int kk = 0; kk < 4; kk++) a[kk] = *(const bf16x8*)(arow + kk * 32);

  f32x4 acc[8];
#pragma unroll
  for (int s = 0; s < 8; s++) acc[s] = {0.f, 0.f, 0.f, 0.f};
#pragma unroll
  for (int s = 0; s < 8; s++) {
    const short* brow = (const short*)W + (size_t)(s * 16 + l16) * D + quad * 8;
#pragma unroll
    for (int kk = 0; kk < 4; kk++) {
      bf16x8 bfv = *(const bf16x8*)(brow + kk * 32);
      acc[s] = __builtin_amdgcn_mfma_f32_16x16x32_bf16(a[kk], bfv, acc[s], 0, 0, 0);
    }
  }
#pragma unroll
  for (int s = 0; s < 8; s++) {
    int n = s * 16 + l16;
    float bv = b2f(bias[n]);
#pragma unroll
    for (int r = 0; r < 4; r++) {
      int rloc = wave * 16 + quad * 4 + r;
      smem[rloc * 129 + n] = acc[s][r] + bv;
    }
  }
  __syncthreads();
  if (threadIdx.x < 64) {
    int r = threadIdx.x;
    float ss = 0.f;
#pragma unroll 8
    for (int kc = 0; kc < D; kc++) { float v = smem[r * 129 + kc]; ss += v * v; }
    float norm = fmaxf(sqrtf(ss), EPS);
    float sq = read_sqrt_c(curv);
    rowscale[r] = tanhf(sq * norm) / (sq * norm);
  }
  __syncthreads();
  bool outbf = FINAL && inputs_are_bf16(curv);
  int mbase = blockIdx.x * 64;
  for (int i = threadIdx.x; i < 64 * D; i += 256) {
    int rloc = i >> 7, col = i & 127;
    int m = mbase + rloc;
    if (m < N_NODES) {
      float val = smem[rloc * 129 + col] * rowscale[rloc];
      if (FINAL) {
        if (outbf) ((unsigned short*)xout)[(size_t)m * D + col] = f2b(val);
        else       ((float*)xout)[(size_t)m * D + col] = val;
      } else {
        ((float*)xout)[(size_t)m * D + col] = val;
      }
    }
  }
}

// --------------------------------------------------------------------------
extern "C" void kernel_launch(void* const* d_in, const int* in_sizes, int n_in,
                              void* d_out, int out_size, void* d_ws, size_t ws_size,
                              hipStream_t stream) {
  const int* neighbors = (const int*)d_in[0];
  const void* node_emb = d_in[1];
  const void* curv     = d_in[2];
  const void* in_w     = d_in[3];  // [L][384][128]
  const void* in_b     = d_in[4];  // [L][384]
  const void* out_w    = d_in[5];  // [L][128][128]
  const void* out_b    = d_in[6];  // [L][128]

  char* ws = (char*)d_ws;
  size_t off = 0;
  auto alloc = [&](size_t bytes) {
    char* p = ws + off; off += (bytes + 255) & ~(size_t)255; return p;
  };
  float*          q_f  = (float*)alloc((size_t)N_PAD * D * 4);
  unsigned short* k_bf = (unsigned short*)alloc((size_t)N_PAD * D * 2);
  unsigned short* v_bf = (unsigned short*)alloc((size_t)N_PAD * D * 2);
  unsigned short* h_bf = (unsigned short*)alloc((size_t)N_PAD * D * 2);
  float*          x1   = (float*)alloc((size_t)N_NODES * D * 4);
  const int n_inw = 2 * 384 * D, n_inb = 2 * 384, n_outw = 2 * D * D, n_outb = 2 * D;
  unsigned short* inw_bf  = (unsigned short*)alloc((size_t)n_inw * 2);
  unsigned short* inb_bf  = (unsigned short*)alloc((size_t)n_inb * 2);
  unsigned short* outw_bf = (unsigned short*)alloc((size_t)n_outw * 2);
  unsigned short* outb_bf = (unsigned short*)alloc((size_t)n_outb * 2);

  dim3 blk(256);
  int nodeBlocks = (N_NODES + 3) / 4;   // 5000
  int mTiles     = (N_NODES + 63) / 64; // 313

  convert_kernel<<<208, blk, 0, stream>>>(
      in_w, inw_bf, n_inw, in_b, inb_bf, n_inb,
      out_w, outw_bf, n_outw, out_b, outb_bf, n_outb, curv);

  for (int l = 0; l < 2; l++) {
    lqkv_kernel<<<mTiles, blk, 0, stream>>>(
        (l == 0) ? node_emb : (const void*)x1, (l == 0) ? 1 : 0,
        inw_bf + (size_t)l * 384 * D, inb_bf + (size_t)l * 384,
        q_f, k_bf, v_bf, curv);

    attn_kernel<<<nodeBlocks, blk, 0, stream>>>(neighbors, q_f, k_bf, v_bf, h_bf);

    if (l == 0)
      outproj_expmap_kernel<false><<<mTiles, blk, 0, stream>>>(
          (const short*)h_bf, outw_bf + (size_t)l * D * D, outb_bf + (size_t)l * D,
          x1, curv);
    else
      outproj_expmap_kernel<true><<<mTiles, blk, 0, stream>>>(
          (const short*)h_bf, outw_bf + (size_t)l * D * D, outb_bf + (size_t)l * D,
          d_out, curv);
  }
}

// Round 4
// 210.003 us; speedup vs baseline: 1.4814x; 1.1211x over previous
//
#include <hip/hip_runtime.h>

#define N_NODES 20000
#define N_PAD   20032      // 313 * 64
#define DEG 32
#define D 128
#define EPS 1e-7f
#define MAX_TANH_ARG (1.0f - 1e-5f)
#define SCORE_SCALE 0.08838834764831845f   // 1/sqrt(128)

typedef short bf16x8 __attribute__((ext_vector_type(8)));
typedef float f32x4 __attribute__((ext_vector_type(4)));

__device__ __forceinline__ float b2f(unsigned short u) {
  union { unsigned int i; float f; } x; x.i = ((unsigned int)u) << 16; return x.f;
}
__device__ __forceinline__ unsigned short f2b(float f) {
  union { float f; unsigned int i; } x; x.f = f;
  unsigned int r = x.i + 0x7FFFu + ((x.i >> 16) & 1u);   // RNE
  return (unsigned short)(r >> 16);
}
// dtype flag: curvature[0] = -1.0. fp32 -> low u16 == 0x0000 ; bf16 -> 0xBF80
__device__ __forceinline__ bool inputs_are_bf16(const void* curv) {
  return *(const unsigned short*)curv != 0;
}
__device__ __forceinline__ float read_sqrt_c(const void* c) {
  unsigned short u = *(const unsigned short*)c;
  float cv = (u == 0) ? *(const float*)c : b2f(u);
  return sqrtf(fabsf(cv));
}
// atanh(x)/x' style fast forms (x in [0, 1-1e-5])
__device__ __forceinline__ float atanh_fast(float x) {
  return 0.5f * __logf((1.f + x) / (1.f - x));
}
// tanh(y)/y for y >= ~0
__device__ __forceinline__ float tanh_over_y(float y) {
  float e = __expf(-2.f * y);
  return (1.f - e) / ((1.f + e) * y);
}

// ---- K_cvt: canonicalize external float arrays to bf16 (dual dtype) ------
__global__ __launch_bounds__(256) void convert_kernel(
    const void* __restrict__ s0, unsigned short* __restrict__ d0, int n0,
    const void* __restrict__ s1, unsigned short* __restrict__ d1, int n1,
    const void* __restrict__ s2, unsigned short* __restrict__ d2, int n2,
    const void* __restrict__ s3, unsigned short* __restrict__ d3, int n3,
    const void* __restrict__ curv) {
  bool bf = inputs_are_bf16(curv);
  int total = n0 + n1 + n2 + n3;
  for (int i = blockIdx.x * 256 + threadIdx.x; i < total; i += gridDim.x * 256) {
    int idx = i;
    const void* s; unsigned short* d;
    if (idx < n0)                { s = s0; d = d0; }
    else if ((idx -= n0) < n1)   { s = s1; d = d1; }
    else if ((idx -= n1) < n2)   { s = s2; d = d2; }
    else { idx -= n2;              s = s3; d = d3; }
    d[idx] = bf ? ((const unsigned short*)s)[idx]
                : f2b(((const float*)s)[idx]);
  }
}

// ------- K1: fused logmap0 + qkv GEMM (t staged in LDS, bf16 MFMA) --------
// grid (313, 3); block 256 = 4 waves. y picks output: 0->q, 1->k, 2->v.
// Stage-1 logmap is recomputed per y (cheap); stage-2 does 2 n-tiles of 64.
__global__ __launch_bounds__(256) void lqkv_kernel(
    const void* __restrict__ xin, int external,
    const unsigned short* __restrict__ W,    // [384][128] bf16 canonical
    const unsigned short* __restrict__ bias, // [384] bf16 canonical
    unsigned short* __restrict__ qout,       // [N_PAD][128] bf16
    unsigned short* __restrict__ kout,       // [N_PAD][128] bf16
    unsigned short* __restrict__ vout,       // [N_PAD][128] bf16
    const void* __restrict__ curv) {
  __shared__ unsigned short t_lds[64 * 136];  // +8 shorts pad per row
  int lane = threadIdx.x & 63;
  int wave = threadIdx.x >> 6;
  int mbase = blockIdx.x * 64;
  bool srcbf = external && inputs_are_bf16(curv);
  float sqc = read_sqrt_c(curv);

  // ---- stage 1: t = logmap0(x) into LDS. 8 lanes per row, 16 cols/lane ---
  {
    int rl = threadIdx.x >> 3;   // 0..31
    int c8 = threadIdx.x & 7;    // 16-col chunk
#pragma unroll
    for (int pass = 0; pass < 2; pass++) {
      int r = pass * 32 + rl;
      int m = mbase + r;
      float xv[16];
      if (m < N_NODES) {
        if (srcbf) {
          const bf16x8* xp = (const bf16x8*)((const unsigned short*)xin + (size_t)m * D + c8 * 16);
          bf16x8 u0 = xp[0], u1 = xp[1];
#pragma unroll
          for (int i = 0; i < 8; i++) { xv[i] = b2f((unsigned short)u0[i]); xv[8 + i] = b2f((unsigned short)u1[i]); }
        } else {
          const float4* xp = (const float4*)((const float*)xin + (size_t)m * D + c8 * 16);
#pragma unroll
          for (int i = 0; i < 4; i++) {
            float4 v = xp[i];
            xv[i * 4 + 0] = v.x; xv[i * 4 + 1] = v.y; xv[i * 4 + 2] = v.z; xv[i * 4 + 3] = v.w;
          }
        }
      } else {
#pragma unroll
        for (int i = 0; i < 16; i++) xv[i] = 0.f;
      }
      float ss = 0.f;
#pragma unroll
      for (int i = 0; i < 16; i++) ss += xv[i] * xv[i];
      ss += __shfl_xor(ss, 1); ss += __shfl_xor(ss, 2); ss += __shfl_xor(ss, 4);
      float norm = fmaxf(sqrtf(ss), EPS);
      float arg  = fminf(sqc * norm, MAX_TANH_ARG);
      float sfac = atanh_fast(arg) / (sqc * norm);
      bf16x8 o0, o1;
#pragma unroll
      for (int i = 0; i < 8; i++) {
        o0[i] = (short)f2b(xv[i] * sfac);
        o1[i] = (short)f2b(xv[8 + i] * sfac);
      }
      *(bf16x8*)&t_lds[r * 136 + c8 * 16]     = o0;
      *(bf16x8*)&t_lds[r * 136 + c8 * 16 + 8] = o1;
    }
  }
  __syncthreads();

  // ---- stage 2: per wave 16m x 128n MFMA (2 n-tiles of 64) ---------------
  int quad = lane >> 4, l16 = lane & 15;
  int m0 = mbase + wave * 16;
  bf16x8 a[4];
#pragma unroll
  for (int kk = 0; kk < 4; kk++)
    a[kk] = *(const bf16x8*)&t_lds[(wave * 16 + l16) * 136 + quad * 8 + kk * 32];

  int nbase = blockIdx.y * 128;   // global col base of this output region
  unsigned short* outp = (blockIdx.y == 0) ? qout : (blockIdx.y == 1) ? kout : vout;

#pragma unroll
  for (int half = 0; half < 2; half++) {
    int n0g = nbase + half * 64;
    f32x4 acc[4];
#pragma unroll
    for (int s = 0; s < 4; s++) acc[s] = {0.f, 0.f, 0.f, 0.f};
#pragma unroll
    for (int s = 0; s < 4; s++) {
      const short* brow = (const short*)W + (size_t)(n0g + s * 16 + l16) * D + quad * 8;
#pragma unroll
      for (int kk = 0; kk < 4; kk++) {
        bf16x8 bfv = *(const bf16x8*)(brow + kk * 32);
        acc[s] = __builtin_amdgcn_mfma_f32_16x16x32_bf16(a[kk], bfv, acc[s], 0, 0, 0);
      }
    }
#pragma unroll
    for (int s = 0; s < 4; s++) {
      int ncol = half * 64 + s * 16 + l16;            // 0..127 within region
      float bv = b2f(bias[nbase + ncol]);
#pragma unroll
      for (int r = 0; r < 4; r++) {
        int m = m0 + quad * 4 + r;
        if (m < N_NODES)
          outp[(size_t)m * D + ncol] = f2b(acc[s][r] + bv);
      }
    }
  }
}

// ---------------- K2: attention (one wave per node, 4 nbrs/group) ---------
__global__ __launch_bounds__(256) void attn_kernel(
    const int* __restrict__ nbrs,
    const unsigned short* __restrict__ qb,   // [N_PAD][128] bf16
    const unsigned short* __restrict__ kb,   // [N_PAD][128] bf16
    const unsigned short* __restrict__ vb,   // [N_PAD][128] bf16
    unsigned short* __restrict__ hout) {     // [N_PAD][128] bf16
  int gid  = blockIdx.x * 256 + threadIdx.x;
  int node = gid >> 6;
  int lane = gid & 63;
  if (node >= N_NODES) return;
  int g = lane >> 4;   // neighbor subgroup 0..3
  int s = lane & 15;   // dim slice: 8 dims at s*8

  float qr[8];
  {
    bf16x8 qv = *(const bf16x8*)(qb + (size_t)node * D + s * 8);
#pragma unroll
    for (int i = 0; i < 8; i++) qr[i] = b2f((unsigned short)qv[i]);
  }
  int idx[8];
#pragma unroll
  for (int jj = 0; jj < 8; jj++) idx[jj] = nbrs[node * DEG + jj * 4 + g];

  // K phase: all 8 gathers in flight, then dot-reduce (16-lane, 4 stages)
  bf16x8 kreg[8];
#pragma unroll
  for (int jj = 0; jj < 8; jj++)
    kreg[jj] = *(const bf16x8*)(kb + (size_t)idx[jj] * D + s * 8);
  float sc[8];
#pragma unroll
  for (int jj = 0; jj < 8; jj++) {
    float p = 0.f;
#pragma unroll
    for (int i = 0; i < 8; i++) p += b2f((unsigned short)kreg[jj][i]) * qr[i];
    p += __shfl_xor(p, 1); p += __shfl_xor(p, 2);
    p += __shfl_xor(p, 4); p += __shfl_xor(p, 8);
    sc[jj] = p * SCORE_SCALE;
  }

  // V gathers issued BEFORE the softmax shuffle chain (overlap latency)
  bf16x8 vreg[8];
#pragma unroll
  for (int jj = 0; jj < 8; jj++)
    vreg[jj] = *(const bf16x8*)(vb + (size_t)idx[jj] * D + s * 8);

  // softmax over 32 (8 local + 2 cross-group stages)
  float mx = sc[0];
#pragma unroll
  for (int jj = 1; jj < 8; jj++) mx = fmaxf(mx, sc[jj]);
  mx = fmaxf(mx, __shfl_xor(mx, 16));
  mx = fmaxf(mx, __shfl_xor(mx, 32));
  float sum = 0.f;
#pragma unroll
  for (int jj = 0; jj < 8; jj++) { sc[jj] = __expf(sc[jj] - mx); sum += sc[jj]; }
  sum += __shfl_xor(sum, 16);
  sum += __shfl_xor(sum, 32);
  float inv = 1.f / sum;

  float hv[8];
#pragma unroll
  for (int i = 0; i < 8; i++) hv[i] = 0.f;
#pragma unroll
  for (int jj = 0; jj < 8; jj++) {
    float aw = sc[jj] * inv;
#pragma unroll
    for (int i = 0; i < 8; i++) hv[i] += aw * b2f((unsigned short)vreg[jj][i]);
  }
#pragma unroll
  for (int i = 0; i < 8; i++) {
    hv[i] += __shfl_xor(hv[i], 16);
    hv[i] += __shfl_xor(hv[i], 32);
  }
  if (g == 0) {
    bf16x8 o;
#pragma unroll
    for (int i = 0; i < 8; i++) o[i] = (short)f2b(hv[i]);
    *(bf16x8*)(hout + (size_t)node * D + s * 8) = o;
  }
}

// ---------------- K3: out_proj + bias + expmap0 (fragment-direct) ---------
// grid 313; block 256 = 4 waves; wave tile 16m x 128n; no LDS.
template <bool FINAL>
__global__ __launch_bounds__(256) void outproj_expmap_kernel(
    const short* __restrict__ h,             // [N_PAD][128] bf16
    const unsigned short* __restrict__ W,    // [128][128] bf16 canonical
    const unsigned short* __restrict__ bias, // [128] bf16 canonical
    void* __restrict__ xout,
    const void* __restrict__ curv) {
  int wave = threadIdx.x >> 6;
  int lane = threadIdx.x & 63;
  int quad = lane >> 4;
  int l16  = lane & 15;
  int m0   = blockIdx.x * 64 + wave * 16;

  bf16x8 a[4];
  const short* arow = h + (size_t)(m0 + l16) * D + quad * 8;
#pragma unroll
  for (int kk = 0; kk < 4; kk++) a[kk] = *(const bf16x8*)(arow + kk * 32);

  f32x4 acc[8];
#pragma unroll
  for (int s = 0; s < 8; s++) acc[s] = {0.f, 0.f, 0.f, 0.f};
#pragma unroll
  for (int s = 0; s < 8; s++) {
    const short* brow = (const short*)W + (size_t)(s * 16 + l16) * D + quad * 8;
#pragma unroll
    for (int kk = 0; kk < 4; kk++) {
      bf16x8 bfv = *(const bf16x8*)(brow + kk * 32);
      acc[s] = __builtin_amdgcn_mfma_f32_16x16x32_bf16(a[kk], bfv, acc[s], 0, 0, 0);
    }
  }
  // bias: col n = s*16 + l16
#pragma unroll
  for (int s = 0; s < 8; s++) {
    float bv = b2f(bias[s * 16 + l16]);
#pragma unroll
    for (int r = 0; r < 4; r++) acc[s][r] += bv;
  }
  // row norms on fragments: row (quad,r) spread across 16 l16-lanes x 8 s
  float sqc = read_sqrt_c(curv);
  float scal[4];
#pragma unroll
  for (int r = 0; r < 4; r++) {
    float ss = 0.f;
#pragma unroll
    for (int s = 0; s < 8; s++) ss += acc[s][r] * acc[s][r];
    ss += __shfl_xor(ss, 1); ss += __shfl_xor(ss, 2);
    ss += __shfl_xor(ss, 4); ss += __shfl_xor(ss, 8);
    float norm = fmaxf(sqrtf(ss), EPS);
    scal[r] = tanh_over_y(sqc * norm);
  }
  bool outbf = FINAL && inputs_are_bf16(curv);
#pragma unroll
  for (int r = 0; r < 4; r++) {
    int m = m0 + quad * 4 + r;
    if (m < N_NODES) {
#pragma unroll
      for (int s = 0; s < 8; s++) {
        float val = acc[s][r] * scal[r];
        int col = s * 16 + l16;
        if (FINAL) {
          if (outbf) ((unsigned short*)xout)[(size_t)m * D + col] = f2b(val);
          else       ((float*)xout)[(size_t)m * D + col] = val;
        } else {
          ((float*)xout)[(size_t)m * D + col] = val;
        }
      }
    }
  }
}

// --------------------------------------------------------------------------
extern "C" void kernel_launch(void* const* d_in, const int* in_sizes, int n_in,
                              void* d_out, int out_size, void* d_ws, size_t ws_size,
                              hipStream_t stream) {
  const int* neighbors = (const int*)d_in[0];
  const void* node_emb = d_in[1];
  const void* curv     = d_in[2];
  const void* in_w     = d_in[3];  // [L][384][128]
  const void* in_b     = d_in[4];  // [L][384]
  const void* out_w    = d_in[5];  // [L][128][128]
  const void* out_b    = d_in[6];  // [L][128]

  char* ws = (char*)d_ws;
  size_t off = 0;
  auto alloc = [&](size_t bytes) {
    char* p = ws + off; off += (bytes + 255) & ~(size_t)255; return p;
  };
  unsigned short* q_bf = (unsigned short*)alloc((size_t)N_PAD * D * 2);
  unsigned short* k_bf = (unsigned short*)alloc((size_t)N_PAD * D * 2);
  unsigned short* v_bf = (unsigned short*)alloc((size_t)N_PAD * D * 2);
  unsigned short* h_bf = (unsigned short*)alloc((size_t)N_PAD * D * 2);
  float*          x1   = (float*)alloc((size_t)N_NODES * D * 4);
  const int n_inw = 2 * 384 * D, n_inb = 2 * 384, n_outw = 2 * D * D, n_outb = 2 * D;
  unsigned short* inw_bf  = (unsigned short*)alloc((size_t)n_inw * 2);
  unsigned short* inb_bf  = (unsigned short*)alloc((size_t)n_inb * 2);
  unsigned short* outw_bf = (unsigned short*)alloc((size_t)n_outw * 2);
  unsigned short* outb_bf = (unsigned short*)alloc((size_t)n_outb * 2);

  dim3 blk(256);
  int nodeBlocks = (N_NODES + 3) / 4;   // 5000
  int mTiles     = (N_NODES + 63) / 64; // 313

  convert_kernel<<<208, blk, 0, stream>>>(
      in_w, inw_bf, n_inw, in_b, inb_bf, n_inb,
      out_w, outw_bf, n_outw, out_b, outb_bf, n_outb, curv);

  for (int l = 0; l < 2; l++) {
    lqkv_kernel<<<dim3(mTiles, 3), blk, 0, stream>>>(
        (l == 0) ? node_emb : (const void*)x1, (l == 0) ? 1 : 0,
        inw_bf + (size_t)l * 384 * D, inb_bf + (size_t)l * 384,
        q_bf, k_bf, v_bf, curv);

    attn_kernel<<<nodeBlocks, blk, 0, stream>>>(neighbors, q_bf, k_bf, v_bf, h_bf);

    if (l == 0)
      outproj_expmap_kernel<false><<<mTiles, blk, 0, stream>>>(
          (const short*)h_bf, outw_bf + (size_t)l * D * D, outb_bf + (size_t)l * D,
          x1, curv);
    else
      outproj_expmap_kernel<true><<<mTiles, blk, 0, stream>>>(
          (const short*)h_bf, outw_bf + (size_t)l * D * D, outb_bf + (size_t)l * D,
          d_out, curv);
  }
}

// Round 5
// 184.645 us; speedup vs baseline: 1.6849x; 1.1373x over previous
//
#include <hip/hip_runtime.h>

#define N_NODES 20000
#define N_PAD   20032      // 313 * 64
#define DEG 32
#define D 128
#define EPS 1e-7f
#define MAX_TANH_ARG (1.0f - 1e-5f)
#define SCORE_SCALE 0.08838834764831845f   // 1/sqrt(128)

typedef short bf16x8 __attribute__((ext_vector_type(8)));
typedef float f32x4 __attribute__((ext_vector_type(4)));

__device__ __forceinline__ float b2f(unsigned short u) {
  union { unsigned int i; float f; } x; x.i = ((unsigned int)u) << 16; return x.f;
}
__device__ __forceinline__ unsigned short f2b(float f) {
  union { float f; unsigned int i; } x; x.f = f;
  unsigned int r = x.i + 0x7FFFu + ((x.i >> 16) & 1u);   // RNE
  return (unsigned short)(r >> 16);
}
// dtype flag: curvature[0] = -1.0. fp32 -> low u16 == 0x0000 ; bf16 -> 0xBF80
__device__ __forceinline__ bool inputs_are_bf16(const void* curv) {
  return *(const unsigned short*)curv != 0;
}
__device__ __forceinline__ float read_sqrt_c(const void* c) {
  unsigned short u = *(const unsigned short*)c;
  float cv = (u == 0) ? *(const float*)c : b2f(u);
  return sqrtf(fabsf(cv));
}
__device__ __forceinline__ float atanh_fast(float x) {
  return 0.5f * __logf((1.f + x) / (1.f - x));
}
__device__ __forceinline__ float tanh_over_y(float y) {
  float e = __expf(-2.f * y);
  return (1.f - e) / ((1.f + e) * y);
}

// ---- fp8 e4m3 encode/decode (HW cvt on gfx950; software fallback) --------
__device__ __forceinline__ unsigned char f2fp8(float v) {
#if __has_builtin(__builtin_amdgcn_cvt_pk_fp8_f32)
  int p = __builtin_amdgcn_cvt_pk_fp8_f32(v, 0.f, 0, false);
  return (unsigned char)(p & 0xFF);
#else
  union { float f; unsigned u; } x; x.f = v;
  unsigned s = (x.u >> 31) << 7;
  float a = fminf(fabsf(v), 448.f);
  int q = (int)rintf(a * 512.f);
  if (q < 8) return (unsigned char)(s | q);      // subnormal
  int e; float m = frexpf(a, &e);                // a = m*2^e, m in [0.5,1)
  int E = e - 1 + 7;
  int mi = (int)rintf(m * 16.f) - 8;
  if (mi == 8) { mi = 0; E += 1; }
  if (E > 15) { E = 15; mi = 6; }
  if (E < 1)  { return (unsigned char)(s | ((int)rintf(a * 512.f) & 7)); }
  return (unsigned char)(s | (E << 3) | mi);
#endif
}
__device__ __forceinline__ void fp8x8_decode(uint2 w, float* f) {
#if __has_builtin(__builtin_amdgcn_cvt_f32_fp8)
  f[0] = __builtin_amdgcn_cvt_f32_fp8((int)w.x, 0);
  f[1] = __builtin_amdgcn_cvt_f32_fp8((int)w.x, 1);
  f[2] = __builtin_amdgcn_cvt_f32_fp8((int)w.x, 2);
  f[3] = __builtin_amdgcn_cvt_f32_fp8((int)w.x, 3);
  f[4] = __builtin_amdgcn_cvt_f32_fp8((int)w.y, 0);
  f[5] = __builtin_amdgcn_cvt_f32_fp8((int)w.y, 1);
  f[6] = __builtin_amdgcn_cvt_f32_fp8((int)w.y, 2);
  f[7] = __builtin_amdgcn_cvt_f32_fp8((int)w.y, 3);
#else
#pragma unroll
  for (int i = 0; i < 8; i++) {
    unsigned char u = (i < 4) ? (unsigned char)(w.x >> (8 * i))
                              : (unsigned char)(w.y >> (8 * (i - 4)));
    int e = (u >> 3) & 15, m = u & 7;
    float mag = e ? ldexpf((float)(8 + m), e - 10) : ldexpf((float)m, -9);
    f[i] = (u & 0x80) ? -mag : mag;
  }
#endif
}

// ---- K_cvt: canonicalize external float arrays to bf16 (dual dtype) ------
__global__ __launch_bounds__(256) void convert_kernel(
    const void* __restrict__ s0, unsigned short* __restrict__ d0, int n0,
    const void* __restrict__ s1, unsigned short* __restrict__ d1, int n1,
    const void* __restrict__ s2, unsigned short* __restrict__ d2, int n2,
    const void* __restrict__ s3, unsigned short* __restrict__ d3, int n3,
    const void* __restrict__ curv) {
  bool bf = inputs_are_bf16(curv);
  int total = n0 + n1 + n2 + n3;
  for (int i = blockIdx.x * 256 + threadIdx.x; i < total; i += gridDim.x * 256) {
    int idx = i;
    const void* s; unsigned short* d;
    if (idx < n0)                { s = s0; d = d0; }
    else if ((idx -= n0) < n1)   { s = s1; d = d1; }
    else if ((idx -= n1) < n2)   { s = s2; d = d2; }
    else { idx -= n2;              s = s3; d = d3; }
    d[idx] = bf ? ((const unsigned short*)s)[idx]
                : f2b(((const float*)s)[idx]);
  }
}

// ------- K1: fused logmap0 + qkv GEMM (t staged in LDS, bf16 MFMA) --------
// grid (313, 3); block 256 = 4 waves. y picks output: 0->q(bf16), 1->k(fp8), 2->v(fp8)
__global__ __launch_bounds__(256) void lqkv_kernel(
    const void* __restrict__ xin, int external,
    const unsigned short* __restrict__ W,    // [384][128] bf16 canonical
    const unsigned short* __restrict__ bias, // [384] bf16 canonical
    unsigned short* __restrict__ qout,       // [N_PAD][128] bf16
    unsigned char* __restrict__ kout,        // [N_PAD][128] fp8
    unsigned char* __restrict__ vout,        // [N_PAD][128] fp8
    const void* __restrict__ curv) {
  __shared__ unsigned short t_lds[64 * 136];  // +8 shorts pad per row
  int lane = threadIdx.x & 63;
  int wave = threadIdx.x >> 6;
  int mbase = blockIdx.x * 64;
  bool srcbf = external && inputs_are_bf16(curv);
  float sqc = read_sqrt_c(curv);

  // ---- stage 1: t = logmap0(x) into LDS. 8 lanes per row, 16 cols/lane ---
  {
    int rl = threadIdx.x >> 3;   // 0..31
    int c8 = threadIdx.x & 7;    // 16-col chunk
#pragma unroll
    for (int pass = 0; pass < 2; pass++) {
      int r = pass * 32 + rl;
      int m = mbase + r;
      float xv[16];
      if (m < N_NODES) {
        if (srcbf) {
          const bf16x8* xp = (const bf16x8*)((const unsigned short*)xin + (size_t)m * D + c8 * 16);
          bf16x8 u0 = xp[0], u1 = xp[1];
#pragma unroll
          for (int i = 0; i < 8; i++) { xv[i] = b2f((unsigned short)u0[i]); xv[8 + i] = b2f((unsigned short)u1[i]); }
        } else {
          const float4* xp = (const float4*)((const float*)xin + (size_t)m * D + c8 * 16);
#pragma unroll
          for (int i = 0; i < 4; i++) {
            float4 v = xp[i];
            xv[i * 4 + 0] = v.x; xv[i * 4 + 1] = v.y; xv[i * 4 + 2] = v.z; xv[i * 4 + 3] = v.w;
          }
        }
      } else {
#pragma unroll
        for (int i = 0; i < 16; i++) xv[i] = 0.f;
      }
      float ss = 0.f;
#pragma unroll
      for (int i = 0; i < 16; i++) ss += xv[i] * xv[i];
      ss += __shfl_xor(ss, 1); ss += __shfl_xor(ss, 2); ss += __shfl_xor(ss, 4);
      float norm = fmaxf(sqrtf(ss), EPS);
      float arg  = fminf(sqc * norm, MAX_TANH_ARG);
      float sfac = atanh_fast(arg) / (sqc * norm);
      bf16x8 o0, o1;
#pragma unroll
      for (int i = 0; i < 8; i++) {
        o0[i] = (short)f2b(xv[i] * sfac);
        o1[i] = (short)f2b(xv[8 + i] * sfac);
      }
      *(bf16x8*)&t_lds[r * 136 + c8 * 16]     = o0;
      *(bf16x8*)&t_lds[r * 136 + c8 * 16 + 8] = o1;
    }
  }
  __syncthreads();

  // ---- stage 2: per wave 16m x 128n MFMA (2 n-tiles of 64) ---------------
  int quad = lane >> 4, l16 = lane & 15;
  int m0 = mbase + wave * 16;
  bf16x8 a[4];
#pragma unroll
  for (int kk = 0; kk < 4; kk++)
    a[kk] = *(const bf16x8*)&t_lds[(wave * 16 + l16) * 136 + quad * 8 + kk * 32];

  int nbase = blockIdx.y * 128;   // global col base of this output region
  bool isq = (blockIdx.y == 0);
  unsigned char* out8 = (blockIdx.y == 1) ? kout : vout;

#pragma unroll
  for (int half = 0; half < 2; half++) {
    int n0g = nbase + half * 64;
    f32x4 acc[4];
#pragma unroll
    for (int s = 0; s < 4; s++) acc[s] = {0.f, 0.f, 0.f, 0.f};
#pragma unroll
    for (int s = 0; s < 4; s++) {
      const short* brow = (const short*)W + (size_t)(n0g + s * 16 + l16) * D + quad * 8;
#pragma unroll
      for (int kk = 0; kk < 4; kk++) {
        bf16x8 bfv = *(const bf16x8*)(brow + kk * 32);
        acc[s] = __builtin_amdgcn_mfma_f32_16x16x32_bf16(a[kk], bfv, acc[s], 0, 0, 0);
      }
    }
#pragma unroll
    for (int s = 0; s < 4; s++) {
      int ncol = half * 64 + s * 16 + l16;            // 0..127 within region
      float bv = b2f(bias[nbase + ncol]);
#pragma unroll
      for (int r = 0; r < 4; r++) {
        int m = m0 + quad * 4 + r;
        if (m < N_NODES) {
          float val = acc[s][r] + bv;
          if (isq) qout[(size_t)m * D + ncol] = f2b(val);
          else     out8[(size_t)m * D + ncol] = f2fp8(val);
        }
      }
    }
  }
}

// ---------------- K2: attention (one wave per node, fp8 k/v tables) -------
__global__ __launch_bounds__(256) void attn_kernel(
    const int* __restrict__ nbrs,
    const unsigned short* __restrict__ qb,   // [N_PAD][128] bf16
    const unsigned char* __restrict__ k8,    // [N_PAD][128] fp8
    const unsigned char* __restrict__ v8,    // [N_PAD][128] fp8
    unsigned short* __restrict__ hout) {     // [N_PAD][128] bf16
  int gid  = blockIdx.x * 256 + threadIdx.x;
  int node = gid >> 6;
  int lane = gid & 63;
  if (node >= N_NODES) return;
  int g = lane >> 4;   // neighbor subgroup 0..3
  int s = lane & 15;   // dim slice: 8 dims at s*8

  float qr[8];
  {
    bf16x8 qv = *(const bf16x8*)(qb + (size_t)node * D + s * 8);
#pragma unroll
    for (int i = 0; i < 8; i++) qr[i] = b2f((unsigned short)qv[i]);
  }
  int idx[8];
#pragma unroll
  for (int jj = 0; jj < 8; jj++) idx[jj] = nbrs[node * DEG + jj * 4 + g];

  // K phase: all 8 gathers in flight, then decode + dot (16-lane reduce)
  uint2 kreg[8];
#pragma unroll
  for (int jj = 0; jj < 8; jj++)
    kreg[jj] = *(const uint2*)(k8 + (size_t)idx[jj] * D + s * 8);
  float sc[8];
#pragma unroll
  for (int jj = 0; jj < 8; jj++) {
    float kf[8];
    fp8x8_decode(kreg[jj], kf);
    float p = 0.f;
#pragma unroll
    for (int i = 0; i < 8; i++) p += kf[i] * qr[i];
    p += __shfl_xor(p, 1); p += __shfl_xor(p, 2);
    p += __shfl_xor(p, 4); p += __shfl_xor(p, 8);
    sc[jj] = p * SCORE_SCALE;
  }

  // V gathers issued BEFORE the softmax shuffle chain (overlap latency)
  uint2 vreg[8];
#pragma unroll
  for (int jj = 0; jj < 8; jj++)
    vreg[jj] = *(const uint2*)(v8 + (size_t)idx[jj] * D + s * 8);

  // softmax over 32 (8 local + 2 cross-group stages)
  float mx = sc[0];
#pragma unroll
  for (int jj = 1; jj < 8; jj++) mx = fmaxf(mx, sc[jj]);
  mx = fmaxf(mx, __shfl_xor(mx, 16));
  mx = fmaxf(mx, __shfl_xor(mx, 32));
  float sum = 0.f;
#pragma unroll
  for (int jj = 0; jj < 8; jj++) { sc[jj] = __expf(sc[jj] - mx); sum += sc[jj]; }
  sum += __shfl_xor(sum, 16);
  sum += __shfl_xor(sum, 32);
  float inv = 1.f / sum;

  float hv[8];
#pragma unroll
  for (int i = 0; i < 8; i++) hv[i] = 0.f;
#pragma unroll
  for (int jj = 0; jj < 8; jj++) {
    float aw = sc[jj] * inv;
    float vf[8];
    fp8x8_decode(vreg[jj], vf);
#pragma unroll
    for (int i = 0; i < 8; i++) hv[i] += aw * vf[i];
  }
#pragma unroll
  for (int i = 0; i < 8; i++) {
    hv[i] += __shfl_xor(hv[i], 16);
    hv[i] += __shfl_xor(hv[i], 32);
  }
  if (g == 0) {
    bf16x8 o;
#pragma unroll
    for (int i = 0; i < 8; i++) o[i] = (short)f2b(hv[i]);
    *(bf16x8*)(hout + (size_t)node * D + s * 8) = o;
  }
}

// ---------------- K3: out_proj + bias + expmap0 (fragment-direct) ---------
template <bool FINAL>
__global__ __launch_bounds__(256) void outproj_expmap_kernel(
    const short* __restrict__ h,             // [N_PAD][128] bf16
    const unsigned short* __restrict__ W,    // [128][128] bf16 canonical
    const unsigned short* __restrict__ bias, // [128] bf16 canonical
    void* __restrict__ xout,
    const void* __restrict__ curv) {
  int wave = threadIdx.x >> 6;
  int lane = threadIdx.x & 63;
  int quad = lane >> 4;
  int l16  = lane & 15;
  int m0   = blockIdx.x * 64 + wave * 16;

  bf16x8 a[4];
  const short* arow = h + (size_t)(m0 + l16) * D + quad * 8;
#pragma unroll
  for (int kk = 0; kk < 4; kk++) a[kk] = *(const bf16x8*)(arow + kk * 32);

  f32x4 acc[8];
#pragma unroll
  for (int s = 0; s < 8; s++) acc[s] = {0.f, 0.f, 0.f, 0.f};
#pragma unroll
  for (int s = 0; s < 8; s++) {
    const short* brow = (const short*)W + (size_t)(s * 16 + l16) * D + quad * 8;
#pragma unroll
    for (int kk = 0; kk < 4; kk++) {
      bf16x8 bfv = *(const bf16x8*)(brow + kk * 32);
      acc[s] = __builtin_amdgcn_mfma_f32_16x16x32_bf16(a[kk], bfv, acc[s], 0, 0, 0);
    }
  }
#pragma unroll
  for (int s = 0; s < 8; s++) {
    float bv = b2f(bias[s * 16 + l16]);
#pragma unroll
    for (int r = 0; r < 4; r++) acc[s][r] += bv;
  }
  float sqc = read_sqrt_c(curv);
  float scal[4];
#pragma unroll
  for (int r = 0; r < 4; r++) {
    float ss = 0.f;
#pragma unroll
    for (int s = 0; s < 8; s++) ss += acc[s][r] * acc[s][r];
    ss += __shfl_xor(ss, 1); ss += __shfl_xor(ss, 2);
    ss += __shfl_xor(ss, 4); ss += __shfl_xor(ss, 8);
    float norm = fmaxf(sqrtf(ss), EPS);
    scal[r] = tanh_over_y(sqc * norm);
  }
  bool outbf = FINAL && inputs_are_bf16(curv);
#pragma unroll
  for (int r = 0; r < 4; r++) {
    int m = m0 + quad * 4 + r;
    if (m < N_NODES) {
#pragma unroll
      for (int s = 0; s < 8; s++) {
        float val = acc[s][r] * scal[r];
        int col = s * 16 + l16;
        if (FINAL) {
          if (outbf) ((unsigned short*)xout)[(size_t)m * D + col] = f2b(val);
          else       ((float*)xout)[(size_t)m * D + col] = val;
        } else {
          ((float*)xout)[(size_t)m * D + col] = val;
        }
      }
    }
  }
}

// --------------------------------------------------------------------------
extern "C" void kernel_launch(void* const* d_in, const int* in_sizes, int n_in,
                              void* d_out, int out_size, void* d_ws, size_t ws_size,
                              hipStream_t stream) {
  const int* neighbors = (const int*)d_in[0];
  const void* node_emb = d_in[1];
  const void* curv     = d_in[2];
  const void* in_w     = d_in[3];  // [L][384][128]
  const void* in_b     = d_in[4];  // [L][384]
  const void* out_w    = d_in[5];  // [L][128][128]
  const void* out_b    = d_in[6];  // [L][128]

  char* ws = (char*)d_ws;
  size_t off = 0;
  auto alloc = [&](size_t bytes) {
    char* p = ws + off; off += (bytes + 255) & ~(size_t)255; return p;
  };
  unsigned short* q_bf = (unsigned short*)alloc((size_t)N_PAD * D * 2);
  unsigned char*  k_f8 = (unsigned char*)alloc((size_t)N_PAD * D);
  unsigned char*  v_f8 = (unsigned char*)alloc((size_t)N_PAD * D);
  unsigned short* h_bf = (unsigned short*)alloc((size_t)N_PAD * D * 2);
  float*          x1   = (float*)alloc((size_t)N_NODES * D * 4);
  const int n_inw = 2 * 384 * D, n_inb = 2 * 384, n_outw = 2 * D * D, n_outb = 2 * D;
  unsigned short* inw_bf  = (unsigned short*)alloc((size_t)n_inw * 2);
  unsigned short* inb_bf  = (unsigned short*)alloc((size_t)n_inb * 2);
  unsigned short* outw_bf = (unsigned short*)alloc((size_t)n_outw * 2);
  unsigned short* outb_bf = (unsigned short*)alloc((size_t)n_outb * 2);

  dim3 blk(256);
  int nodeBlocks = (N_NODES + 3) / 4;   // 5000
  int mTiles     = (N_NODES + 63) / 64; // 313

  convert_kernel<<<208, blk, 0, stream>>>(
      in_w, inw_bf, n_inw, in_b, inb_bf, n_inb,
      out_w, outw_bf, n_outw, out_b, outb_bf, n_outb, curv);

  for (int l = 0; l < 2; l++) {
    lqkv_kernel<<<dim3(mTiles, 3), blk, 0, stream>>>(
        (l == 0) ? node_emb : (const void*)x1, (l == 0) ? 1 : 0,
        inw_bf + (size_t)l * 384 * D, inb_bf + (size_t)l * 384,
        q_bf, k_f8, v_f8, curv);

    attn_kernel<<<nodeBlocks, blk, 0, stream>>>(neighbors, q_bf, k_f8, v_f8, h_bf);

    if (l == 0)
      outproj_expmap_kernel<false><<<mTiles, blk, 0, stream>>>(
          (const short*)h_bf, outw_bf + (size_t)l * D * D, outb_bf + (size_t)l * D,
          x1, curv);
    else
      outproj_expmap_kernel<true><<<mTiles, blk, 0, stream>>>(
          (const short*)h_bf, outw_bf + (size_t)l * D * D, outb_bf + (size_t)l * D,
          d_out, curv);
  }
}

// Round 6
// 184.517 us; speedup vs baseline: 1.6861x; 1.0007x over previous
//
#include <hip/hip_runtime.h>

#define N_NODES 20000
#define N_PAD   20032      // 313 * 64
#define DEG 32
#define D 128
#define EPS 1e-7f
#define MAX_TANH_ARG (1.0f - 1e-5f)
#define SCORE_SCALE 0.08838834764831845f   // 1/sqrt(128)

typedef short bf16x8 __attribute__((ext_vector_type(8)));
typedef float f32x4 __attribute__((ext_vector_type(4)));

__device__ __forceinline__ float b2f(unsigned short u) {
  union { unsigned int i; float f; } x; x.i = ((unsigned int)u) << 16; return x.f;
}
__device__ __forceinline__ unsigned short f2b(float f) {
  union { float f; unsigned int i; } x; x.f = f;
  unsigned int r = x.i + 0x7FFFu + ((x.i >> 16) & 1u);   // RNE
  return (unsigned short)(r >> 16);
}
// dtype flag: curvature[0] = -1.0. fp32 -> low u16 == 0x0000 ; bf16 -> 0xBF80
__device__ __forceinline__ bool inputs_are_bf16(const void* curv) {
  return *(const unsigned short*)curv != 0;
}
__device__ __forceinline__ float read_sqrt_c(const void* c) {
  unsigned short u = *(const unsigned short*)c;
  float cv = (u == 0) ? *(const float*)c : b2f(u);
  return sqrtf(fabsf(cv));
}
__device__ __forceinline__ float atanh_fast(float x) {
  return 0.5f * __logf((1.f + x) / (1.f - x));
}
__device__ __forceinline__ float tanh_over_y(float y) {
  float e = __expf(-2.f * y);
  return (1.f - e) / ((1.f + e) * y);
}

// ---- fp8 e4m3 encode/decode (HW cvt on gfx950; software fallback) --------
__device__ __forceinline__ unsigned char f2fp8(float v) {
#if __has_builtin(__builtin_amdgcn_cvt_pk_fp8_f32)
  int p = __builtin_amdgcn_cvt_pk_fp8_f32(v, 0.f, 0, false);
  return (unsigned char)(p & 0xFF);
#else
  union { float f; unsigned u; } x; x.f = v;
  unsigned s = (x.u >> 31) << 7;
  float a = fminf(fabsf(v), 448.f);
  int q = (int)rintf(a * 512.f);
  if (q < 8) return (unsigned char)(s | q);      // subnormal
  int e; float m = frexpf(a, &e);                // a = m*2^e, m in [0.5,1)
  int E = e - 1 + 7;
  int mi = (int)rintf(m * 16.f) - 8;
  if (mi == 8) { mi = 0; E += 1; }
  if (E > 15) { E = 15; mi = 6; }
  if (E < 1)  { return (unsigned char)(s | ((int)rintf(a * 512.f) & 7)); }
  return (unsigned char)(s | (E << 3) | mi);
#endif
}
__device__ __forceinline__ void fp8x8_decode(uint2 w, float* f) {
#if __has_builtin(__builtin_amdgcn_cvt_f32_fp8)
  f[0] = __builtin_amdgcn_cvt_f32_fp8((int)w.x, 0);
  f[1] = __builtin_amdgcn_cvt_f32_fp8((int)w.x, 1);
  f[2] = __builtin_amdgcn_cvt_f32_fp8((int)w.x, 2);
  f[3] = __builtin_amdgcn_cvt_f32_fp8((int)w.x, 3);
  f[4] = __builtin_amdgcn_cvt_f32_fp8((int)w.y, 0);
  f[5] = __builtin_amdgcn_cvt_f32_fp8((int)w.y, 1);
  f[6] = __builtin_amdgcn_cvt_f32_fp8((int)w.y, 2);
  f[7] = __builtin_amdgcn_cvt_f32_fp8((int)w.y, 3);
#else
#pragma unroll
  for (int i = 0; i < 8; i++) {
    unsigned char u = (i < 4) ? (unsigned char)(w.x >> (8 * i))
                              : (unsigned char)(w.y >> (8 * (i - 4)));
    int e = (u >> 3) & 15, m = u & 7;
    float mag = e ? ldexpf((float)(8 + m), e - 10) : ldexpf((float)m, -9);
    f[i] = (u & 0x80) ? -mag : mag;
  }
#endif
}

// ---- K_cvt: canonicalize external float arrays to bf16 (dual dtype) ------
__global__ __launch_bounds__(256) void convert_kernel(
    const void* __restrict__ s0, unsigned short* __restrict__ d0, int n0,
    const void* __restrict__ s1, unsigned short* __restrict__ d1, int n1,
    const void* __restrict__ s2, unsigned short* __restrict__ d2, int n2,
    const void* __restrict__ s3, unsigned short* __restrict__ d3, int n3,
    const void* __restrict__ curv) {
  bool bf = inputs_are_bf16(curv);
  int total = n0 + n1 + n2 + n3;
  for (int i = blockIdx.x * 256 + threadIdx.x; i < total; i += gridDim.x * 256) {
    int idx = i;
    const void* s; unsigned short* d;
    if (idx < n0)                { s = s0; d = d0; }
    else if ((idx -= n0) < n1)   { s = s1; d = d1; }
    else if ((idx -= n1) < n2)   { s = s2; d = d2; }
    else { idx -= n2;              s = s3; d = d3; }
    d[idx] = bf ? ((const unsigned short*)s)[idx]
                : f2b(((const float*)s)[idx]);
  }
}

// ---- shared epilogue for qkv GEMM waves ----------------------------------
__device__ __forceinline__ void qkv_store(
    int m0, int quad, int l16, int nbase, bool isq,
    const f32x4* acc,  // 2 halves x ... laid out as acc[half*4+s]
    const unsigned short* bias, unsigned short* qout, unsigned char* out8) {
#pragma unroll
  for (int half = 0; half < 2; half++) {
#pragma unroll
    for (int s = 0; s < 4; s++) {
      int ncol = half * 64 + s * 16 + l16;
      float bv = b2f(bias[nbase + ncol]);
#pragma unroll
      for (int r = 0; r < 4; r++) {
        int m = m0 + quad * 4 + r;
        if (m < N_NODES) {
          float val = acc[half * 4 + s][r] + bv;
          if (isq) qout[(size_t)m * D + ncol] = f2b(val);
          else     out8[(size_t)m * D + ncol] = f2fp8(val);
        }
      }
    }
  }
}

__device__ __forceinline__ void qkv_mfma(
    const bf16x8* a, const unsigned short* W, int nbase, int quad, int l16,
    f32x4* acc) {
#pragma unroll
  for (int half = 0; half < 2; half++) {
    int n0g = nbase + half * 64;
#pragma unroll
    for (int s = 0; s < 4; s++) {
      acc[half * 4 + s] = {0.f, 0.f, 0.f, 0.f};
      const short* brow = (const short*)W + (size_t)(n0g + s * 16 + l16) * D + quad * 8;
#pragma unroll
      for (int kk = 0; kk < 4; kk++) {
        bf16x8 bfv = *(const bf16x8*)(brow + kk * 32);
        acc[half * 4 + s] = __builtin_amdgcn_mfma_f32_16x16x32_bf16(a[kk], bfv, acc[half * 4 + s], 0, 0, 0);
      }
    }
  }
}

// ------- K1a (layer 0): fused logmap0 + qkv GEMM (t staged in LDS) --------
// grid (313, 3); block 256 = 4 waves. y: 0->q(bf16), 1->k(fp8), 2->v(fp8)
__global__ __launch_bounds__(256) void lqkv_kernel(
    const void* __restrict__ xin,
    const unsigned short* __restrict__ W,    // [384][128] bf16 canonical
    const unsigned short* __restrict__ bias, // [384] bf16 canonical
    unsigned short* __restrict__ qout,
    unsigned char* __restrict__ kout,
    unsigned char* __restrict__ vout,
    const void* __restrict__ curv) {
  __shared__ unsigned short t_lds[64 * 136];
  int lane = threadIdx.x & 63;
  int wave = threadIdx.x >> 6;
  int mbase = blockIdx.x * 64;
  bool srcbf = inputs_are_bf16(curv);
  float sqc = read_sqrt_c(curv);

  {
    int rl = threadIdx.x >> 3;   // 0..31
    int c8 = threadIdx.x & 7;    // 16-col chunk
#pragma unroll
    for (int pass = 0; pass < 2; pass++) {
      int r = pass * 32 + rl;
      int m = mbase + r;
      float xv[16];
      if (m < N_NODES) {
        if (srcbf) {
          const bf16x8* xp = (const bf16x8*)((const unsigned short*)xin + (size_t)m * D + c8 * 16);
          bf16x8 u0 = xp[0], u1 = xp[1];
#pragma unroll
          for (int i = 0; i < 8; i++) { xv[i] = b2f((unsigned short)u0[i]); xv[8 + i] = b2f((unsigned short)u1[i]); }
        } else {
          const float4* xp = (const float4*)((const float*)xin + (size_t)m * D + c8 * 16);
#pragma unroll
          for (int i = 0; i < 4; i++) {
            float4 v = xp[i];
            xv[i * 4 + 0] = v.x; xv[i * 4 + 1] = v.y; xv[i * 4 + 2] = v.z; xv[i * 4 + 3] = v.w;
          }
        }
      } else {
#pragma unroll
        for (int i = 0; i < 16; i++) xv[i] = 0.f;
      }
      float ss = 0.f;
#pragma unroll
      for (int i = 0; i < 16; i++) ss += xv[i] * xv[i];
      ss += __shfl_xor(ss, 1); ss += __shfl_xor(ss, 2); ss += __shfl_xor(ss, 4);
      float norm = fmaxf(sqrtf(ss), EPS);
      float arg  = fminf(sqc * norm, MAX_TANH_ARG);
      float sfac = atanh_fast(arg) / (sqc * norm);
      bf16x8 o0, o1;
#pragma unroll
      for (int i = 0; i < 8; i++) {
        o0[i] = (short)f2b(xv[i] * sfac);
        o1[i] = (short)f2b(xv[8 + i] * sfac);
      }
      *(bf16x8*)&t_lds[r * 136 + c8 * 16]     = o0;
      *(bf16x8*)&t_lds[r * 136 + c8 * 16 + 8] = o1;
    }
  }
  __syncthreads();

  int quad = lane >> 4, l16 = lane & 15;
  int m0 = mbase + wave * 16;
  bf16x8 a[4];
#pragma unroll
  for (int kk = 0; kk < 4; kk++)
    a[kk] = *(const bf16x8*)&t_lds[(wave * 16 + l16) * 136 + quad * 8 + kk * 32];

  int nbase = blockIdx.y * 128;
  f32x4 acc[8];
  qkv_mfma(a, W, nbase, quad, l16, acc);
  qkv_store(m0, quad, l16, nbase, blockIdx.y == 0, acc, bias,
            qout, (blockIdx.y == 1) ? kout : vout);
}

// ------- K1b (layer 1): qkv GEMM directly from t (= prev h', bf16) --------
// No logmap: logmap0(expmap0(v)) == v, so t1 = out_proj output of layer 0.
__global__ __launch_bounds__(256) void qkv_direct_kernel(
    const unsigned short* __restrict__ t,    // [N_PAD][128] bf16
    const unsigned short* __restrict__ W,
    const unsigned short* __restrict__ bias,
    unsigned short* __restrict__ qout,
    unsigned char* __restrict__ kout,
    unsigned char* __restrict__ vout) {
  int lane = threadIdx.x & 63;
  int wave = threadIdx.x >> 6;
  int quad = lane >> 4, l16 = lane & 15;
  int m0 = blockIdx.x * 64 + wave * 16;

  bf16x8 a[4];
  const short* arow = (const short*)t + (size_t)(m0 + l16) * D + quad * 8;
#pragma unroll
  for (int kk = 0; kk < 4; kk++) a[kk] = *(const bf16x8*)(arow + kk * 32);

  int nbase = blockIdx.y * 128;
  f32x4 acc[8];
  qkv_mfma(a, W, nbase, quad, l16, acc);
  qkv_store(m0, quad, l16, nbase, blockIdx.y == 0, acc, bias,
            qout, (blockIdx.y == 1) ? kout : vout);
}

// ---------------- K2: attention (one wave per node, fp8 k/v tables) -------
__global__ __launch_bounds__(256) void attn_kernel(
    const int* __restrict__ nbrs,
    const unsigned short* __restrict__ qb,   // [N_PAD][128] bf16
    const unsigned char* __restrict__ k8,    // [N_PAD][128] fp8
    const unsigned char* __restrict__ v8,    // [N_PAD][128] fp8
    unsigned short* __restrict__ hout) {     // [N_PAD][128] bf16
  int gid  = blockIdx.x * 256 + threadIdx.x;
  int node = gid >> 6;
  int lane = gid & 63;
  if (node >= N_NODES) return;
  int g = lane >> 4;   // neighbor subgroup 0..3
  int s = lane & 15;   // dim slice: 8 dims at s*8

  float qr[8];
  {
    bf16x8 qv = *(const bf16x8*)(qb + (size_t)node * D + s * 8);
#pragma unroll
    for (int i = 0; i < 8; i++) qr[i] = b2f((unsigned short)qv[i]);
  }
  int idx[8];
#pragma unroll
  for (int jj = 0; jj < 8; jj++) idx[jj] = nbrs[node * DEG + jj * 4 + g];

  // ALL 16 gathers issued before any compute (max loads in flight)
  uint2 kreg[8], vreg[8];
#pragma unroll
  for (int jj = 0; jj < 8; jj++)
    kreg[jj] = *(const uint2*)(k8 + (size_t)idx[jj] * D + s * 8);
#pragma unroll
  for (int jj = 0; jj < 8; jj++)
    vreg[jj] = *(const uint2*)(v8 + (size_t)idx[jj] * D + s * 8);

  float sc[8];
#pragma unroll
  for (int jj = 0; jj < 8; jj++) {
    float kf[8];
    fp8x8_decode(kreg[jj], kf);
    float p = 0.f;
#pragma unroll
    for (int i = 0; i < 8; i++) p += kf[i] * qr[i];
    p += __shfl_xor(p, 1); p += __shfl_xor(p, 2);
    p += __shfl_xor(p, 4); p += __shfl_xor(p, 8);
    sc[jj] = p * SCORE_SCALE;
  }

  float mx = sc[0];
#pragma unroll
  for (int jj = 1; jj < 8; jj++) mx = fmaxf(mx, sc[jj]);
  mx = fmaxf(mx, __shfl_xor(mx, 16));
  mx = fmaxf(mx, __shfl_xor(mx, 32));
  float sum = 0.f;
#pragma unroll
  for (int jj = 0; jj < 8; jj++) { sc[jj] = __expf(sc[jj] - mx); sum += sc[jj]; }
  sum += __shfl_xor(sum, 16);
  sum += __shfl_xor(sum, 32);
  float inv = 1.f / sum;

  float hv[8];
#pragma unroll
  for (int i = 0; i < 8; i++) hv[i] = 0.f;
#pragma unroll
  for (int jj = 0; jj < 8; jj++) {
    float aw = sc[jj] * inv;
    float vf[8];
    fp8x8_decode(vreg[jj], vf);
#pragma unroll
    for (int i = 0; i < 8; i++) hv[i] += aw * vf[i];
  }
#pragma unroll
  for (int i = 0; i < 8; i++) {
    hv[i] += __shfl_xor(hv[i], 16);
    hv[i] += __shfl_xor(hv[i], 32);
  }
  if (g == 0) {
    bf16x8 o;
#pragma unroll
    for (int i = 0; i < 8; i++) o[i] = (short)f2b(hv[i]);
    *(bf16x8*)(hout + (size_t)node * D + s * 8) = o;
  }
}

// ---------------- K3: out_proj + bias (+ expmap0 only when FINAL) ---------
// MODE 0: write t_{l+1} = h' as bf16 (expmap+logmap cancel at boundary)
// MODE 1: final output: expmap0 then store in harness dtype
template <int MODE>
__global__ __launch_bounds__(256) void outproj_kernel(
    const short* __restrict__ h,
    const unsigned short* __restrict__ W,
    const unsigned short* __restrict__ bias,
    void* __restrict__ xout,
    const void* __restrict__ curv) {
  int wave = threadIdx.x >> 6;
  int lane = threadIdx.x & 63;
  int quad = lane >> 4;
  int l16  = lane & 15;
  int m0   = blockIdx.x * 64 + wave * 16;

  bf16x8 a[4];
  const short* arow = h + (size_t)(m0 + l16) * D + quad * 8;
#pragma unroll
  for (int kk = 0; kk < 4; kk++) a[kk] = *(const bf16x8*)(arow + kk * 32);

  f32x4 acc[8];
#pragma unroll
  for (int s = 0; s < 8; s++) acc[s] = {0.f, 0.f, 0.f, 0.f};
#pragma unroll
  for (int s = 0; s < 8; s++) {
    const short* brow = (const short*)W + (size_t)(s * 16 + l16) * D + quad * 8;
#pragma unroll
    for (int kk = 0; kk < 4; kk++) {
      bf16x8 bfv = *(const bf16x8*)(brow + kk * 32);
      acc[s] = __builtin_amdgcn_mfma_f32_16x16x32_bf16(a[kk], bfv, acc[s], 0, 0, 0);
    }
  }
#pragma unroll
  for (int s = 0; s < 8; s++) {
    float bv = b2f(bias[s * 16 + l16]);
#pragma unroll
    for (int r = 0; r < 4; r++) acc[s][r] += bv;
  }
  float scal[4];
  if (MODE == 1) {
    float sqc = read_sqrt_c(curv);
#pragma unroll
    for (int r = 0; r < 4; r++) {
      float ss = 0.f;
#pragma unroll
      for (int s = 0; s < 8; s++) ss += acc[s][r] * acc[s][r];
      ss += __shfl_xor(ss, 1); ss += __shfl_xor(ss, 2);
      ss += __shfl_xor(ss, 4); ss += __shfl_xor(ss, 8);
      float norm = fmaxf(sqrtf(ss), EPS);
      scal[r] = tanh_over_y(sqc * norm);
    }
  }
  bool outbf = (MODE == 1) && inputs_are_bf16(curv);
#pragma unroll
  for (int r = 0; r < 4; r++) {
    int m = m0 + quad * 4 + r;
    if (m < N_NODES) {
#pragma unroll
      for (int s = 0; s < 8; s++) {
        int col = s * 16 + l16;
        if (MODE == 0) {
          ((unsigned short*)xout)[(size_t)m * D + col] = f2b(acc[s][r]);
        } else {
          float val = acc[s][r] * scal[r];
          if (outbf) ((unsigned short*)xout)[(size_t)m * D + col] = f2b(val);
          else       ((float*)xout)[(size_t)m * D + col] = val;
        }
      }
    }
  }
}

// --------------------------------------------------------------------------
extern "C" void kernel_launch(void* const* d_in, const int* in_sizes, int n_in,
                              void* d_out, int out_size, void* d_ws, size_t ws_size,
                              hipStream_t stream) {
  const int* neighbors = (const int*)d_in[0];
  const void* node_emb = d_in[1];
  const void* curv     = d_in[2];
  const void* in_w     = d_in[3];
  const void* in_b     = d_in[4];
  const void* out_w    = d_in[5];
  const void* out_b    = d_in[6];

  char* ws = (char*)d_ws;
  size_t off = 0;
  auto alloc = [&](size_t bytes) {
    char* p = ws + off; off += (bytes + 255) & ~(size_t)255; return p;
  };
  unsigned short* q_bf = (unsigned short*)alloc((size_t)N_PAD * D * 2);
  unsigned char*  k_f8 = (unsigned char*)alloc((size_t)N_PAD * D);
  unsigned char*  v_f8 = (unsigned char*)alloc((size_t)N_PAD * D);
  unsigned short* h_bf = (unsigned short*)alloc((size_t)N_PAD * D * 2);
  unsigned short* t1_bf = (unsigned short*)alloc((size_t)N_PAD * D * 2);
  const int n_inw = 2 * 384 * D, n_inb = 2 * 384, n_outw = 2 * D * D, n_outb = 2 * D;
  unsigned short* inw_bf  = (unsigned short*)alloc((size_t)n_inw * 2);
  unsigned short* inb_bf  = (unsigned short*)alloc((size_t)n_inb * 2);
  unsigned short* outw_bf = (unsigned short*)alloc((size_t)n_outw * 2);
  unsigned short* outb_bf = (unsigned short*)alloc((size_t)n_outb * 2);

  dim3 blk(256);
  int nodeBlocks = (N_NODES + 3) / 4;   // 5000
  int mTiles     = (N_NODES + 63) / 64; // 313

  convert_kernel<<<208, blk, 0, stream>>>(
      in_w, inw_bf, n_inw, in_b, inb_bf, n_inb,
      out_w, outw_bf, n_outw, out_b, outb_bf, n_outb, curv);

  // ---- layer 0 ----
  lqkv_kernel<<<dim3(mTiles, 3), blk, 0, stream>>>(
      node_emb, inw_bf, inb_bf, q_bf, k_f8, v_f8, curv);
  attn_kernel<<<nodeBlocks, blk, 0, stream>>>(neighbors, q_bf, k_f8, v_f8, h_bf);
  outproj_kernel<0><<<mTiles, blk, 0, stream>>>(
      (const short*)h_bf, outw_bf, outb_bf, t1_bf, curv);

  // ---- layer 1 ----
  qkv_direct_kernel<<<dim3(mTiles, 3), blk, 0, stream>>>(
      t1_bf, inw_bf + (size_t)384 * D, inb_bf + 384, q_bf, k_f8, v_f8);
  attn_kernel<<<nodeBlocks, blk, 0, stream>>>(neighbors, q_bf, k_f8, v_f8, h_bf);
  outproj_kernel<1><<<mTiles, blk, 0, stream>>>(
      (const short*)h_bf, outw_bf + (size_t)D * D, outb_bf + D, d_out, curv);
}